// Round 6
// baseline (506.678 us; speedup 1.0000x reference)
//
#include <hip/hip_runtime.h>
#include <hip/hip_fp16.h>
#include <math.h>

typedef _Float16 half_t;
typedef _Float16 h8_t __attribute__((ext_vector_type(8)));
typedef _Float16 h4_t __attribute__((ext_vector_type(4)));
typedef float f4_t __attribute__((ext_vector_type(4)));

#define MFMA16(a, b, c) __builtin_amdgcn_mfma_f32_16x16x32_f16(a, b, c, 0, 0, 0)

static constexpr int kB = 4;
static constexpr int kS = 2048;
static constexpr int kD = 1024;
static constexpr int BM = 256;   // A-rows per block
static constexpr int BN = 128;   // B-rows per block
static constexpr int BK = 32;
// LDS tile layout [kb 0..3][row][8 halves] — measured 0 bank conflicts (R2-R5).
// A-tile: 256x32 halves = 8192 (16 KB); B-tile: 128x32 = 4096 (8 KB).

// ---------- NT GEMM core: C[256,128] += A[256,K]*B[128,K]^T, 512 thr / 8 waves ----------
// Wave grid 4x2 (wave-tile 64x64). VGPR prefetch of tile k+1 overlaps MFMA phase.
template <bool SPLIT>
__device__ __forceinline__ void gemm_core(const half_t* __restrict__ Ahi,
                                          const half_t* __restrict__ Alo, int lda,
                                          const half_t* __restrict__ Bhi,
                                          const half_t* __restrict__ Blo, int ldb,
                                          int k_iters, half_t* sm, f4_t acc[4][4]) {
  half_t* sAh = sm;             // [0, 8192)
  half_t* sBh = sm + 8192;      // [8192, 12288)
  half_t* sAl = sm + 12288;     // SPLIT only
  half_t* sBl = sm + 20480;
  const int t = threadIdx.x;
  const int lane = t & 63;
  const int wid = t >> 6;
  const int wm = (wid & 3) * 64;
  const int wn = (wid >> 2) * 64;
  const int fr = lane & 15;
  const int quad = lane >> 4;
  // staging: A cells (256 rows x 4 kb) = 1024 -> 2/thread; B cells 512 -> 1/thread
  const int rowA = t & 255, kbA = t >> 8;      // kbA in {0,1}; second cell kbA+2
  const int rowB = t & 127, kbB = t >> 7;      // kbB in {0..3}
  const size_t gA1 = (size_t)rowA * lda + kbA * 8;
  const size_t gA2 = gA1 + 16;                 // (kbA+2)*8
  const size_t gB  = (size_t)rowB * ldb + kbB * 8;
  const int lA1 = kbA * 2048 + rowA * 8;
  const int lA2 = lA1 + 2 * 2048;
  const int lB  = kbB * 1024 + rowB * 8;
  const int fA = quad * 2048 + fr * 8;
  const int fB = quad * 1024 + fr * 8;

  h8_t rA1, rA2, rB1, rAl1, rAl2, rBl1;
  rA1 = *(const h8_t*)&Ahi[gA1];
  rA2 = *(const h8_t*)&Ahi[gA2];
  rB1 = *(const h8_t*)&Bhi[gB];
  if constexpr (SPLIT) {
    rAl1 = *(const h8_t*)&Alo[gA1];
    rAl2 = *(const h8_t*)&Alo[gA2];
    rBl1 = *(const h8_t*)&Blo[gB];
  }

  for (int kk = 0; kk < k_iters; ++kk) {
    *(h8_t*)&sAh[lA1] = rA1;
    *(h8_t*)&sAh[lA2] = rA2;
    *(h8_t*)&sBh[lB] = rB1;
    if constexpr (SPLIT) {
      *(h8_t*)&sAl[lA1] = rAl1;
      *(h8_t*)&sAl[lA2] = rAl2;
      *(h8_t*)&sBl[lB] = rBl1;
    }
    __syncthreads();
    if (kk + 1 < k_iters) {  // prefetch next tile; flies under the MFMA phase
      const size_t ko = (size_t)(kk + 1) * BK;
      rA1 = *(const h8_t*)&Ahi[gA1 + ko];
      rA2 = *(const h8_t*)&Ahi[gA2 + ko];
      rB1 = *(const h8_t*)&Bhi[gB + ko];
      if constexpr (SPLIT) {
        rAl1 = *(const h8_t*)&Alo[gA1 + ko];
        rAl2 = *(const h8_t*)&Alo[gA2 + ko];
        rBl1 = *(const h8_t*)&Blo[gB + ko];
      }
    }
    h8_t a[4], b[4], al[4], bl[4];
#pragma unroll
    for (int i = 0; i < 4; ++i) {
      a[i] = *(h8_t*)&sAh[fA + (wm + i * 16) * 8];
      b[i] = *(h8_t*)&sBh[fB + (wn + i * 16) * 8];
      if constexpr (SPLIT) {
        al[i] = *(h8_t*)&sAl[fA + (wm + i * 16) * 8];
        bl[i] = *(h8_t*)&sBl[fB + (wn + i * 16) * 8];
      }
    }
#pragma unroll
    for (int i = 0; i < 4; ++i)
#pragma unroll
      for (int j = 0; j < 4; ++j) {
        acc[i][j] = MFMA16(a[i], b[j], acc[i][j]);
        if constexpr (SPLIT) {
          acc[i][j] = MFMA16(a[i], bl[j], acc[i][j]);
          acc[i][j] = MFMA16(al[i], b[j], acc[i][j]);
        }
      }
    __syncthreads();
  }
}

// ---------- Q = X * WQK^T (split), 256 blocks: XCD x owns mi = x+8k, ni-inner ----------
__global__ __launch_bounds__(512, 1) void gemm_q_kernel(
    const half_t* __restrict__ Xhi, const half_t* __restrict__ Xlo,
    const half_t* __restrict__ Whi, const half_t* __restrict__ Wlo,
    half_t* __restrict__ Qhi, half_t* __restrict__ Qlo) {
  __shared__ half_t sm[24576];  // 48 KB
  const int x = blockIdx.x & 7, s = blockIdx.x >> 3;
  const int mi = x + 8 * (s >> 3), ni = s & 7;
  const size_t arow = (size_t)mi * BM;
  const size_t brow = (size_t)ni * BN;
  f4_t acc[4][4] = {};
  gemm_core<true>(Xhi + arow * kD, Xlo + arow * kD, kD,
                  Whi + brow * kD, Wlo + brow * kD, kD, kD / BK, sm, acc);
  const int lane = threadIdx.x & 63;
  const int wid = threadIdx.x >> 6;
  const int wm = (wid & 3) * 64, wn = (wid >> 2) * 64;
  const int c16 = lane & 15, r4 = (lane >> 4) * 4;
#pragma unroll
  for (int i = 0; i < 4; ++i)
#pragma unroll
    for (int j = 0; j < 4; ++j)
#pragma unroll
      for (int r = 0; r < 4; ++r) {
        const size_t row = arow + wm + i * 16 + r4 + r;
        const size_t col = brow + wn + j * 16 + c16;
        const float qv = acc[i][j][r];
        const half_t qh = (half_t)qv;
        const half_t ql = (half_t)(qv - (float)qh);
        const size_t idx = row * kD + col;
        Qhi[idx] = qh;
        Qlo[idx] = ql;
      }
}

// ---------- V = X * WOV^T (fp16 single), transposed out: Vt[b][e][t] ----------
__global__ __launch_bounds__(512, 1) void gemm_v_kernel(
    const half_t* __restrict__ Xhi, const half_t* __restrict__ Whi,
    half_t* __restrict__ Vt) {
  __shared__ half_t sm[12288];  // 24 KB
  const int x = blockIdx.x & 7, s = blockIdx.x >> 3;
  const int mi = x + 8 * (s >> 3), ni = s & 7;
  const size_t arow = (size_t)mi * BM;
  const size_t brow = (size_t)ni * BN;
  f4_t acc[4][4] = {};
  gemm_core<false>(Xhi + arow * kD, nullptr, kD, Whi + brow * kD, nullptr, kD,
                   kD / BK, sm, acc);
  const int lane = threadIdx.x & 63;
  const int wid = threadIdx.x >> 6;
  const int wm = (wid & 3) * 64, wn = (wid >> 2) * 64;
  const int c16 = lane & 15, r4 = (lane >> 4) * 4;
#pragma unroll
  for (int i = 0; i < 4; ++i)
#pragma unroll
    for (int j = 0; j < 4; ++j)
#pragma unroll
      for (int r = 0; r < 4; ++r) {
        const size_t row = arow + wm + i * 16 + r4 + r;  // 0..8191
        const size_t col = brow + wn + j * 16 + c16;     // e
        const size_t bi = row >> 11;
        const size_t ss = row & 2047;
        Vt[bi * (size_t)kD * kS + col * kS + ss] = (half_t)acc[i][j][r];
      }
}

// ---------- Sc = 32 * Q * X^T, causal tiles (256-row x 128-col) ----------
// 288 blocks. XCD x owns combos {x, x+8}; combo c = (bi,pair p); within a pair
// (m=p, m=7-p) tiles are n-interleaved so consecutive same-XCD blocks share X.
__global__ __launch_bounds__(512, 1) void gemm_score_kernel(
    const half_t* __restrict__ Qhi, const half_t* __restrict__ Qlo,
    const half_t* __restrict__ Xhi, const half_t* __restrict__ Xlo,
    float* __restrict__ Sc) {
  const int x = blockIdx.x & 7;
  const int s = blockIdx.x >> 3;           // 0..35
  const int c = (s < 18) ? x : x + 8;      // combo 0..15
  const int j = (s < 18) ? s : s - 18;     // 0..17
  const int bi = c >> 2, p = c & 3;
  int m, n;
  if (j < 4 * p + 4) {
    n = j >> 1;
    m = (j & 1) ? 7 - p : p;
  } else {
    n = j - 2 * p - 2;
    m = 7 - p;
  }
  __shared__ half_t sm[24576];  // 48 KB
  const size_t arow = (size_t)bi * kS + (size_t)m * BM;
  const size_t brow = (size_t)bi * kS + (size_t)n * BN;
  f4_t acc[4][4] = {};
  gemm_core<true>(Qhi + arow * kD, Qlo + arow * kD, kD,
                  Xhi + brow * kD, Xlo + brow * kD, kD, kD / BK, sm, acc);
  float* out = Sc + (size_t)bi * kS * kS;
  const int lane = threadIdx.x & 63;
  const int wid = threadIdx.x >> 6;
  const int wm = (wid & 3) * 64, wn = (wid >> 2) * 64;
  const int c16 = lane & 15, r4 = (lane >> 4) * 4;
#pragma unroll
  for (int i = 0; i < 4; ++i)
#pragma unroll
    for (int jj = 0; jj < 4; ++jj)
#pragma unroll
      for (int r = 0; r < 4; ++r) {
        const int row = m * BM + wm + i * 16 + r4 + r;
        const int col = n * BN + wn + jj * 16 + c16;
        out[(size_t)row * kS + col] = 32.0f * acc[i][jj][r];
      }
}

// ---------- row softmax (causal), in-place on d_out A region + fp16 copy ----------
__global__ __launch_bounds__(256) void softmax_kernel(float* __restrict__ A,
                                                      half_t* __restrict__ Ah) {
  const int rgl = blockIdx.x;  // 0..8191
  const int s = rgl & 2047;
  float* row = A + (size_t)rgl * kS;
  half_t* hrow = Ah + (size_t)rgl * kS;
  const int tid = threadIdx.x;
  const int n = s + 1;
  float v[8];
  float mx = -INFINITY;
#pragma unroll
  for (int i = 0; i < 8; ++i) {
    const int t = tid + i * 256;
    v[i] = (t < n) ? row[t] : -INFINITY;
    mx = fmaxf(mx, v[i]);
  }
  for (int off = 32; off; off >>= 1) mx = fmaxf(mx, __shfl_xor(mx, off));
  __shared__ float red[8];
  const int lane = tid & 63, wid = tid >> 6;
  if (lane == 0) red[wid] = mx;
  __syncthreads();
  if (tid == 0) {
    float mm = fmaxf(fmaxf(red[0], red[1]), fmaxf(red[2], red[3]));
    red[4] = mm;
  }
  __syncthreads();
  mx = red[4];
  float sum = 0.0f;
#pragma unroll
  for (int i = 0; i < 8; ++i) {
    v[i] = (tid + i * 256 < n) ? __expf(v[i] - mx) : 0.0f;
    sum += v[i];
  }
  for (int off = 32; off; off >>= 1) sum += __shfl_xor(sum, off);
  __syncthreads();
  if (lane == 0) red[wid] = sum;
  __syncthreads();
  if (tid == 0) red[5] = 1.0f / (red[0] + red[1] + red[2] + red[3]);
  __syncthreads();
  const float inv = red[5];
#pragma unroll
  for (int i = 0; i < 8; ++i) {
    const int t = tid + i * 256;
    const float a = v[i] * inv;  // zero for t > s
    row[t] = a;
    hrow[t] = (half_t)a;
  }
}

// ---------- Y = A * V (causal K), epilogue Out0 = X + Y ----------
// 256 blocks. XCD x owns m = x (even batches) / 7-x (odd) for work balance;
// n-inner keeps the A-panel fixed across consecutive same-XCD blocks.
__global__ __launch_bounds__(512, 1) void gemm_y_kernel(
    const half_t* __restrict__ Ah, const half_t* __restrict__ Vt,
    const float* __restrict__ X, float* __restrict__ Out) {
  const int x = blockIdx.x & 7, s = blockIdx.x >> 3;  // s 0..31
  const int bi = s >> 3, n = s & 7;
  const int m = (bi & 1) ? (7 - x) : x;
  __shared__ half_t sm[12288];  // 24 KB
  const size_t abase = ((size_t)bi * kS + (size_t)m * BM) * kS;
  const size_t bbase = ((size_t)bi * kD + (size_t)n * BN) * kS;
  f4_t acc[4][4] = {};
  gemm_core<false>(Ah + abase, nullptr, kS, Vt + bbase, nullptr, kS,
                   (m + 1) * BM / BK, sm, acc);
  const size_t obase = (size_t)bi * kS * kD;
  const int lane = threadIdx.x & 63;
  const int wid = threadIdx.x >> 6;
  const int wm = (wid & 3) * 64, wn = (wid >> 2) * 64;
  const int c16 = lane & 15, r4 = (lane >> 4) * 4;
#pragma unroll
  for (int i = 0; i < 4; ++i)
#pragma unroll
    for (int j = 0; j < 4; ++j)
#pragma unroll
      for (int r = 0; r < 4; ++r) {
        const size_t row = (size_t)m * BM + wm + i * 16 + r4 + r;
        const size_t col = (size_t)n * BN + wn + j * 16 + c16;
        const size_t idx = obase + row * kD + col;
        Out[idx] = X[idx] + acc[i][j][r];
      }
}

// ---------- fp32 -> fp16 hi/lo split (and hi-only convert) ----------
__global__ __launch_bounds__(256) void split_kernel(const float* __restrict__ x,
                                                    half_t* __restrict__ hi,
                                                    half_t* __restrict__ lo, int n4) {
  const int i = blockIdx.x * 256 + threadIdx.x;
  if (i >= n4) return;
  const float4 v = ((const float4*)x)[i];
  const float vv[4] = {v.x, v.y, v.z, v.w};
  h4_t h, l;
#pragma unroll
  for (int j = 0; j < 4; ++j) {
    const half_t hh = (half_t)vv[j];
    h[j] = hh;
    l[j] = (half_t)(vv[j] - (float)hh);
  }
  ((h4_t*)hi)[i] = h;
  ((h4_t*)lo)[i] = l;
}

__global__ __launch_bounds__(256) void cvt_kernel(const float* __restrict__ x,
                                                  half_t* __restrict__ hi, int n4) {
  const int i = blockIdx.x * 256 + threadIdx.x;
  if (i >= n4) return;
  const float4 v = ((const float4*)x)[i];
  h4_t h;
  h[0] = (half_t)v.x; h[1] = (half_t)v.y; h[2] = (half_t)v.z; h[3] = (half_t)v.w;
  ((h4_t*)hi)[i] = h;
}

extern "C" void kernel_launch(void* const* d_in, const int* in_sizes, int n_in,
                              void* d_out, int out_size, void* d_ws, size_t ws_size,
                              hipStream_t stream) {
  const float* X   = (const float*)d_in[0];
  // d_in[1] = causal mask: deterministic (tril) — unused
  const float* WQK = (const float*)d_in[2];
  const float* WOV = (const float*)d_in[3];

  constexpr size_t nX = (size_t)kB * kS * kD;   // 8388608
  constexpr size_t nW = (size_t)kD * kD;        // 1048576
  constexpr size_t nA = (size_t)kB * kS * kS;   // 16777216

  float* out0 = (float*)d_out;        // X + Y
  float* outA = out0 + nX;            // A (also raw-score scratch)

  half_t* ws = (half_t*)d_ws;
  half_t* Xhi = ws; ws += nX;
  half_t* Xlo = ws; ws += nX;
  half_t* Qhi = ws; ws += nX;
  half_t* Qlo = ws; ws += nX;
  half_t* Whi = ws; ws += nW;
  half_t* Wlo = ws; ws += nW;
  half_t* WVh = ws; ws += nW;
  half_t* Vt  = ws; ws += nX;
  half_t* Ah  = ws; ws += nA;
  const size_t need_bytes = (size_t)((char*)ws - (char*)d_ws);
  if (ws_size < need_bytes) return;

  split_kernel<<<(int)(nX / 4 / 256), 256, 0, stream>>>(X, Xhi, Xlo, (int)(nX / 4));
  split_kernel<<<(int)(nW / 4 / 256), 256, 0, stream>>>(WQK, Whi, Wlo, (int)(nW / 4));
  cvt_kernel<<<(int)(nW / 4 / 256), 256, 0, stream>>>(WOV, WVh, (int)(nW / 4));

  gemm_q_kernel<<<256, 512, 0, stream>>>(Xhi, Xlo, Whi, Wlo, Qhi, Qlo);
  gemm_v_kernel<<<256, 512, 0, stream>>>(Xhi, WVh, Vt);
  gemm_score_kernel<<<288, 512, 0, stream>>>(Qhi, Qlo, Xhi, Xlo, outA);
  softmax_kernel<<<kB * kS, 256, 0, stream>>>(outA, Ah);
  gemm_y_kernel<<<256, 512, 0, stream>>>(Ah, Vt, X, out0);
}